// Round 2
// baseline (97.783 us; speedup 1.0000x reference)
//
#include <hip/hip_runtime.h>

// ---------------- Kernel 1: score head ----------------
// One thread = one triplet. x flat: [N*20, 12] fp32.
// s[i] = bl[1] + dot(x[i*12 .. i*12+12], Wl[:,1])
__global__ __launch_bounds__(256) void score_kernel(
    const float* __restrict__ x,    // [N*20*12]
    const float* __restrict__ Wl,   // [12,2]
    const float* __restrict__ bl,   // [2]
    float* __restrict__ s,          // [N*20]
    int n_trip)
{
    const int i = blockIdx.x * blockDim.x + threadIdx.x;
    if (i >= n_trip) return;

    // lane-uniform -> scalar loads
    float wl[12];
#pragma unroll
    for (int f = 0; f < 12; ++f) wl[f] = Wl[f * 2 + 1];
    const float blv = bl[1];

    const float4* xt = reinterpret_cast<const float4*>(x + (size_t)i * 12);
    float4 a0 = xt[0];
    float4 a1 = xt[1];
    float4 a2 = xt[2];
    float acc = blv;
    acc += a0.x * wl[0] + a0.y * wl[1] + a0.z * wl[2]  + a0.w * wl[3];
    acc += a1.x * wl[4] + a1.y * wl[5] + a1.z * wl[6]  + a1.w * wl[7];
    acc += a2.x * wl[8] + a2.y * wl[9] + a2.z * wl[10] + a2.w * wl[11];
    s[i] = acc;
}

// ---------------- Kernel 2: MLP 20->80->40->21 ----------------
// One thread = one event. Reads s[e,20], writes out[e,21].
__global__ __launch_bounds__(256) void mlp_kernel(
    const float* __restrict__ s_in, // [N,20]
    const float* __restrict__ W1,   // [80,20]
    const float* __restrict__ b1,   // [80]
    const float* __restrict__ W2,   // [40,80]
    const float* __restrict__ b2,   // [40]
    const float* __restrict__ W3,   // [21,40]
    const float* __restrict__ b3,   // [21]
    float* __restrict__ out,        // [N,21]
    int n)
{
    const int ev = blockIdx.x * blockDim.x + threadIdx.x;
    if (ev >= n) return;

    float s[20];
    const float4* sp = reinterpret_cast<const float4*>(s_in + (size_t)ev * 20);
#pragma unroll
    for (int q = 0; q < 5; ++q) {
        float4 v = sp[q];
        s[q * 4 + 0] = v.x; s[q * 4 + 1] = v.y;
        s[q * 4 + 2] = v.z; s[q * 4 + 3] = v.w;
    }

    float h1[80];
#pragma unroll
    for (int j = 0; j < 80; ++j) {
        const float* __restrict__ w = W1 + j * 20;
        float acc = b1[j];
#pragma unroll
        for (int k = 0; k < 20; ++k) acc += s[k] * w[k];
        h1[j] = fmaxf(acc, 0.0f);
    }

    float h2[40];
#pragma unroll
    for (int j = 0; j < 40; ++j) {
        const float* __restrict__ w = W2 + j * 80;
        float acc = b2[j];
#pragma unroll
        for (int k = 0; k < 80; ++k) acc += h1[k] * w[k];
        h2[j] = fmaxf(acc, 0.0f);
    }

    float* __restrict__ oe = out + (size_t)ev * 21;
#pragma unroll
    for (int j = 0; j < 21; ++j) {
        const float* __restrict__ w = W3 + j * 40;
        float acc = b3[j];
#pragma unroll
        for (int k = 0; k < 40; ++k) acc += h2[k] * w[k];
        oe[j] = acc;
    }
}

extern "C" void kernel_launch(void* const* d_in, const int* in_sizes, int n_in,
                              void* d_out, int out_size, void* d_ws, size_t ws_size,
                              hipStream_t stream) {
    const float* x  = (const float*)d_in[0];
    const float* Wl = (const float*)d_in[1];
    const float* bl = (const float*)d_in[2];
    const float* W1 = (const float*)d_in[3];
    const float* b1 = (const float*)d_in[4];
    const float* W2 = (const float*)d_in[5];
    const float* b2 = (const float*)d_in[6];
    const float* W3 = (const float*)d_in[7];
    const float* b3 = (const float*)d_in[8];
    float* out = (float*)d_out;
    float* s   = (float*)d_ws;      // [N*20] fp32 = 8 MB scratch

    const int n = in_sizes[0] / 240;   // events
    const int n_trip = n * 20;         // triplets

    {
        const int block = 256;
        const int grid = (n_trip + block - 1) / block;
        score_kernel<<<grid, block, 0, stream>>>(x, Wl, bl, s, n_trip);
    }
    {
        const int block = 256;
        const int grid = (n + block - 1) / block;
        mlp_kernel<<<grid, block, 0, stream>>>(s, W1, b1, W2, b2, W3, b3, out, n);
    }
}

// Round 3
// 97.616 us; speedup vs baseline: 1.0017x; 1.0017x over previous
//
#include <hip/hip_runtime.h>

// ---------------- Kernel 1: score head ----------------
// One thread = one triplet. x flat: [N*20, 12] fp32.
// s[i] = bl[1] + dot(x[i*12 .. i*12+12], Wl[:,1])
__global__ __launch_bounds__(256) void score_kernel(
    const float* __restrict__ x,    // [N*20*12]
    const float* __restrict__ Wl,   // [12,2]
    const float* __restrict__ bl,   // [2]
    float* __restrict__ s,          // [N*20]
    int n_trip)
{
    const int i = blockIdx.x * blockDim.x + threadIdx.x;
    if (i >= n_trip) return;

    // lane-uniform -> scalar loads
    float wl[12];
#pragma unroll
    for (int f = 0; f < 12; ++f) wl[f] = Wl[f * 2 + 1];
    const float blv = bl[1];

    const float4* xt = reinterpret_cast<const float4*>(x + (size_t)i * 12);
    float4 a0 = xt[0];
    float4 a1 = xt[1];
    float4 a2 = xt[2];
    float acc = blv;
    acc += a0.x * wl[0] + a0.y * wl[1] + a0.z * wl[2]  + a0.w * wl[3];
    acc += a1.x * wl[4] + a1.y * wl[5] + a1.z * wl[6]  + a1.w * wl[7];
    acc += a2.x * wl[8] + a2.y * wl[9] + a2.z * wl[10] + a2.w * wl[11];
    s[i] = acc;
}

// ---------------- Kernel 2: MLP 20->80->40->21 ----------------
// One thread = one event. block=64 + launch_bounds(64,1) so the register
// allocator can keep s[20]+h1[80]+h2[40] (~140 floats) fully in VGPRs —
// at block=256 the default heuristic capped us at 68 VGPRs and spilled
// h1/h2 to scratch (the 96us pathology of round 2).
__global__ __launch_bounds__(64, 1) void mlp_kernel(
    const float* __restrict__ s_in, // [N,20]
    const float* __restrict__ W1,   // [80,20]
    const float* __restrict__ b1,   // [80]
    const float* __restrict__ W2,   // [40,80]
    const float* __restrict__ b2,   // [40]
    const float* __restrict__ W3,   // [21,40]
    const float* __restrict__ b3,   // [21]
    float* __restrict__ out,        // [N,21]
    int n)
{
    const int ev = blockIdx.x * blockDim.x + threadIdx.x;
    if (ev >= n) return;

    float s[20];
    const float4* sp = reinterpret_cast<const float4*>(s_in + (size_t)ev * 20);
#pragma unroll
    for (int q = 0; q < 5; ++q) {
        float4 v = sp[q];
        s[q * 4 + 0] = v.x; s[q * 4 + 1] = v.y;
        s[q * 4 + 2] = v.z; s[q * 4 + 3] = v.w;
    }

    float h1[80];
#pragma unroll
    for (int j = 0; j < 80; ++j) {
        const float* __restrict__ w = W1 + j * 20;
        float acc = b1[j];
#pragma unroll
        for (int k = 0; k < 20; ++k) acc += s[k] * w[k];
        h1[j] = fmaxf(acc, 0.0f);
    }

    float h2[40];
#pragma unroll
    for (int j = 0; j < 40; ++j) {
        const float* __restrict__ w = W2 + j * 80;
        float acc = b2[j];
#pragma unroll
        for (int k = 0; k < 80; ++k) acc += h1[k] * w[k];
        h2[j] = fmaxf(acc, 0.0f);
    }

    float* __restrict__ oe = out + (size_t)ev * 21;
#pragma unroll
    for (int j = 0; j < 21; ++j) {
        const float* __restrict__ w = W3 + j * 40;
        float acc = b3[j];
#pragma unroll
        for (int k = 0; k < 40; ++k) acc += h2[k] * w[k];
        oe[j] = acc;
    }
}

extern "C" void kernel_launch(void* const* d_in, const int* in_sizes, int n_in,
                              void* d_out, int out_size, void* d_ws, size_t ws_size,
                              hipStream_t stream) {
    const float* x  = (const float*)d_in[0];
    const float* Wl = (const float*)d_in[1];
    const float* bl = (const float*)d_in[2];
    const float* W1 = (const float*)d_in[3];
    const float* b1 = (const float*)d_in[4];
    const float* W2 = (const float*)d_in[5];
    const float* b2 = (const float*)d_in[6];
    const float* W3 = (const float*)d_in[7];
    const float* b3 = (const float*)d_in[8];
    float* out = (float*)d_out;
    float* s   = (float*)d_ws;      // [N*20] fp32 = 8 MB scratch

    const int n = in_sizes[0] / 240;   // events
    const int n_trip = n * 20;         // triplets

    {
        const int block = 256;
        const int grid = (n_trip + block - 1) / block;
        score_kernel<<<grid, block, 0, stream>>>(x, Wl, bl, s, n_trip);
    }
    {
        const int block = 64;
        const int grid = (n + block - 1) / block;
        mlp_kernel<<<grid, block, 0, stream>>>(s, W1, b1, W2, b2, W3, b3, out, n);
    }
}

// Round 4
// 92.182 us; speedup vs baseline: 1.0608x; 1.0589x over previous
//
#include <hip/hip_runtime.h>

// ---------------- Kernel 1: score head + weight transpose ----------------
// One thread = one triplet. x flat: [N*20, 12] fp32.
// s[i] = bl[1] + dot(x[i*12..+12], Wl[:,1])
// The LAST block additionally transposes W2 -> W2T [80][40] and
// W3 -> W3T [40][21] into workspace (needed for column-streaming MLP).
__global__ __launch_bounds__(256) void score_kernel(
    const float* __restrict__ x,    // [N*20*12]
    const float* __restrict__ Wl,   // [12,2]
    const float* __restrict__ bl,   // [2]
    const float* __restrict__ W2,   // [40,80]
    const float* __restrict__ W3,   // [21,40]
    float* __restrict__ s,          // [N*20]
    float* __restrict__ W2t,        // [80*40]
    float* __restrict__ W3t,        // [40*21]
    int n_trip)
{
    const int i = blockIdx.x * blockDim.x + threadIdx.x;

    // last block does the tiny transposes (runs concurrently with scoring)
    if (blockIdx.x == gridDim.x - 1) {
        for (int idx = threadIdx.x; idx < 80 * 40; idx += blockDim.x) {
            int k = idx / 40, j = idx - k * 40;     // W2t[k][j] = W2[j][k]
            W2t[idx] = W2[j * 80 + k];
        }
        for (int idx = threadIdx.x; idx < 40 * 21; idx += blockDim.x) {
            int k = idx / 21, j = idx - k * 21;     // W3t[k][j] = W3[j][k]
            W3t[idx] = W3[j * 40 + k];
        }
    }

    if (i >= n_trip) return;

    float wl[12];
#pragma unroll
    for (int f = 0; f < 12; ++f) wl[f] = Wl[f * 2 + 1];
    const float blv = bl[1];

    const float4* xt = reinterpret_cast<const float4*>(x + (size_t)i * 12);
    float4 a0 = xt[0];
    float4 a1 = xt[1];
    float4 a2 = xt[2];
    float acc = blv;
    acc += a0.x * wl[0] + a0.y * wl[1] + a0.z * wl[2]  + a0.w * wl[3];
    acc += a1.x * wl[4] + a1.y * wl[5] + a1.z * wl[6]  + a1.w * wl[7];
    acc += a2.x * wl[8] + a2.y * wl[9] + a2.z * wl[10] + a2.w * wl[11];
    s[i] = acc;
}

// ---------------- Kernel 2: MLP 20->80->40->21, column-streamed ----------------
// One thread = one event. h1 is NEVER materialized: for each hidden-1 neuron k
// we compute its activation and immediately accumulate into the 40 h2 regs.
// All register arrays (s[20], h2[40], o[21]) are indexed only with
// compile-time constants -> guaranteed VGPR residency (no scratch).
__global__ __launch_bounds__(256, 2) void mlp_kernel(
    const float* __restrict__ s_in, // [N,20]
    const float* __restrict__ W1,   // [80,20] row-major (row = h1 neuron)
    const float* __restrict__ b1,   // [80]
    const float* __restrict__ W2t,  // [80,40] (row k = h1 index)
    const float* __restrict__ b2,   // [40]
    const float* __restrict__ W3t,  // [40,21] (row k = h2 index)
    const float* __restrict__ b3,   // [21]
    float* __restrict__ out,        // [N,21]
    int n)
{
    const int ev = blockIdx.x * blockDim.x + threadIdx.x;
    if (ev >= n) return;

    float s[20];
    const float4* sp = reinterpret_cast<const float4*>(s_in + (size_t)ev * 20);
#pragma unroll
    for (int q = 0; q < 5; ++q) {
        float4 v = sp[q];
        s[q * 4 + 0] = v.x; s[q * 4 + 1] = v.y;
        s[q * 4 + 2] = v.z; s[q * 4 + 3] = v.w;
    }

    float h2[40];
#pragma unroll
    for (int j = 0; j < 40; ++j) h2[j] = b2[j];

    // Phase A: stream over the 80 hidden-1 neurons (rolled loop is fine:
    // only pointers depend on k2, all array indices are static).
    for (int k2 = 0; k2 < 80; ++k2) {
        const float* __restrict__ w1r = W1 + k2 * 20;
        float a = b1[k2];
#pragma unroll
        for (int k = 0; k < 20; ++k) a += s[k] * w1r[k];
        a = fmaxf(a, 0.0f);
        const float* __restrict__ w2r = W2t + k2 * 40;
#pragma unroll
        for (int j = 0; j < 40; ++j) h2[j] += a * w2r[j];
    }

    // relu h2 (static indices)
#pragma unroll
    for (int j = 0; j < 40; ++j) h2[j] = fmaxf(h2[j], 0.0f);

    // Phase B: 40 -> 21, fully unrolled (840 FMA, static indices everywhere)
    float o[21];
#pragma unroll
    for (int j = 0; j < 21; ++j) o[j] = b3[j];
#pragma unroll
    for (int k3 = 0; k3 < 40; ++k3) {
        const float a = h2[k3];
        const float* __restrict__ w3r = W3t + k3 * 21;
#pragma unroll
        for (int j = 0; j < 21; ++j) o[j] += a * w3r[j];
    }

    float* __restrict__ oe = out + (size_t)ev * 21;
#pragma unroll
    for (int j = 0; j < 21; ++j) oe[j] = o[j];
}

extern "C" void kernel_launch(void* const* d_in, const int* in_sizes, int n_in,
                              void* d_out, int out_size, void* d_ws, size_t ws_size,
                              hipStream_t stream) {
    const float* x  = (const float*)d_in[0];
    const float* Wl = (const float*)d_in[1];
    const float* bl = (const float*)d_in[2];
    const float* W1 = (const float*)d_in[3];
    const float* b1 = (const float*)d_in[4];
    const float* W2 = (const float*)d_in[5];
    const float* b2 = (const float*)d_in[6];
    const float* W3 = (const float*)d_in[7];
    const float* b3 = (const float*)d_in[8];
    float* out = (float*)d_out;

    const int n = in_sizes[0] / 240;   // events
    const int n_trip = n * 20;         // triplets

    float* s   = (float*)d_ws;                 // [N*20] fp32 = 8 MB
    float* W2t = s + (size_t)n_trip;           // [80*40]
    float* W3t = W2t + 80 * 40;                // [40*21]

    {
        const int block = 256;
        const int grid = (n_trip + block - 1) / block;
        score_kernel<<<grid, block, 0, stream>>>(x, Wl, bl, W2, W3,
                                                 s, W2t, W3t, n_trip);
    }
    {
        const int block = 256;
        const int grid = (n + block - 1) / block;
        mlp_kernel<<<grid, block, 0, stream>>>(s, W1, b1, W2t, b2, W3t, b3, out, n);
    }
}

// Round 5
// 39.915 us; speedup vs baseline: 2.4498x; 2.3095x over previous
//
#include <hip/hip_runtime.h>

typedef _Float16 f16;
typedef _Float16 f16x8 __attribute__((ext_vector_type(8)));
typedef float    f32x4 __attribute__((ext_vector_type(4)));

// Weight-fragment buffer layout (f16, in d_ws after s16):
//   Wfrag1: [5 nt][64 lane][8 j]              = 2560   (GEMM1 B: W1T padded K 20->32)
//   Wfrag2: [3 ks][3 nt][64][8]               = 4608   (GEMM2 B: W2T padded K 80->96, N 40->48)
//   Wfrag3: [2 ks][2 nt][64][8]               = 2048   (GEMM3 B: W3T padded K 40->64, N 21->32)
#define WF1_OFF 0
#define WF2_OFF 2560
#define WF3_OFF 7168
#define WF_TOTAL 9216

// ---------------- prep: build per-lane MFMA weight fragments ----------------
// Fragment convention (must match mlp kernel's A-frags):
//   lane l supplies k = (l>>4)*8 + j, j=0..7 ; B col n = l&15 ; A row m = l&15.
// Correctness is invariant to the HW's true intra-lane k-map as long as A and B
// use the same map (both do).
__global__ void prep_kernel(const float* __restrict__ W1,   // [80,20]
                            const float* __restrict__ W2,   // [40,80]
                            const float* __restrict__ W3,   // [21,40]
                            f16* __restrict__ wf) {
    const int tid = threadIdx.x;
    for (int idx = tid; idx < 5 * 512; idx += blockDim.x) {
        int j = idx & 7, lane = (idx >> 3) & 63, nt = idx >> 9;
        int n = nt * 16 + (lane & 15);
        int k = (lane >> 4) * 8 + j;
        wf[WF1_OFF + idx] = (k < 20) ? (f16)W1[n * 20 + k] : (f16)0.f;
    }
    for (int idx = tid; idx < 9 * 512; idx += blockDim.x) {
        int j = idx & 7, lane = (idx >> 3) & 63;
        int grp = idx >> 9, nt = grp % 3, ks = grp / 3;
        int n = nt * 16 + (lane & 15);
        int k = ks * 32 + (lane >> 4) * 8 + j;
        wf[WF2_OFF + idx] = (k < 80 && n < 40) ? (f16)W2[n * 80 + k] : (f16)0.f;
    }
    for (int idx = tid; idx < 4 * 512; idx += blockDim.x) {
        int j = idx & 7, lane = (idx >> 3) & 63;
        int grp = idx >> 9, nt = grp % 2, ks = grp / 2;
        int n = nt * 16 + (lane & 15);
        int k = ks * 32 + (lane >> 4) * 8 + j;
        wf[WF3_OFF + idx] = (k < 40 && n < 21) ? (f16)W3[n * 40 + k] : (f16)0.f;
    }
}

// ---------------- score: s16[e][32] = f16(bl[1] + x[e,t]·Wl[:,1]), pad 20-31 = 0 ----
__global__ __launch_bounds__(256) void score_kernel(
    const float* __restrict__ x, const float* __restrict__ Wl,
    const float* __restrict__ bl, f16* __restrict__ s16, int n_trip) {
    const int i = blockIdx.x * blockDim.x + threadIdx.x;
    if (i >= n_trip) return;
    const int e = i / 20, t = i - e * 20;

    float wl[12];
#pragma unroll
    for (int f = 0; f < 12; ++f) wl[f] = Wl[f * 2 + 1];

    const float4* xt = reinterpret_cast<const float4*>(x + (size_t)i * 12);
    float4 a0 = xt[0], a1 = xt[1], a2 = xt[2];
    float acc = bl[1];
    acc += a0.x * wl[0] + a0.y * wl[1] + a0.z * wl[2]  + a0.w * wl[3];
    acc += a1.x * wl[4] + a1.y * wl[5] + a1.z * wl[6]  + a1.w * wl[7];
    acc += a2.x * wl[8] + a2.y * wl[9] + a2.z * wl[10] + a2.w * wl[11];
    s16[(size_t)e * 32 + t] = (f16)acc;
    if (t < 12) s16[(size_t)e * 32 + 20 + t] = (f16)0.f;   // zero K-pad
}

// ---------------- MLP: fused 3-GEMM via f16 MFMA ----------------
// Block = 256 thr = 4 waves; wave w owns 16 events. 18 MFMAs per wave.
// C/D layout (m89-verified): lane holds col = lane&15, rows = (lane>>4)*4 + r.
#define WAVES 4
__global__ __launch_bounds__(256) void mlp_mfma_kernel(
    const f16* __restrict__ s16,   // [N][32]
    const f16* __restrict__ wf,    // [WF_TOTAL]
    const float* __restrict__ b1, const float* __restrict__ b2,
    const float* __restrict__ b3,
    float* __restrict__ out, int n) {

    __shared__ __align__(16) f16 wfl[WF_TOTAL];
    // H tiles: [k-chunk gg][16 rows][8 k] per wave -> A-frag read is one
    // contiguous ds_read_b128 per lane (conflict-free).
    __shared__ __align__(16) f16 h1t[WAVES][12][16][8];  // K 0..95 (80..95 zero)
    __shared__ __align__(16) f16 h2t[WAVES][8][16][8];   // K 0..63 (40..63 zero)

    const int wave = threadIdx.x >> 6;
    const int lane = threadIdx.x & 63;
    const int lrow = lane & 15;   // tile row (A) / col (B,C)
    const int lg   = lane >> 4;   // k-group / C row-group

    // coalesced copy of weight fragments global -> LDS (1152 x 16B)
    {
        const uint4* src = reinterpret_cast<const uint4*>(wf);
        uint4* dst = reinterpret_cast<uint4*>(wfl);
        for (int idx = threadIdx.x; idx < WF_TOTAL * 2 / 16; idx += blockDim.x)
            dst[idx] = src[idx];
    }
    // zero the K-pad blocks (uninit LDS * 0-weight could be NaN)
    {
        int* z1 = reinterpret_cast<int*>(&h1t[wave][10][0][0]);  // gg 10,11
        z1[lane] = 0; z1[lane + 64] = 0;
        int* z2 = reinterpret_cast<int*>(&h2t[wave][5][0][0]);   // gg 5,6,7
        z2[lane] = 0; z2[lane + 64] = 0; z2[lane + 128] = 0;
    }
    __syncthreads();

    const int ev0 = (blockIdx.x * WAVES + wave) * 16;
    if (ev0 >= n) return;   // N % 16 == 0 -> waves fully valid or fully out

    const f16x8* bfrag = reinterpret_cast<const f16x8*>(wfl);
    const f32x4 zero4 = {0.f, 0.f, 0.f, 0.f};

    // ---- GEMM1: [16 ev x 32k] x [32k x 80] ----
    f16x8 a1 = reinterpret_cast<const f16x8*>(s16 + (size_t)(ev0 + lrow) * 32)[lg];
    f32x4 acc1[5];
#pragma unroll
    for (int nt = 0; nt < 5; ++nt)
        acc1[nt] = __builtin_amdgcn_mfma_f32_16x16x32_f16(
            a1, bfrag[(WF1_OFF / 8) + nt * 64 + lane], zero4, 0, 0, 0);
#pragma unroll
    for (int nt = 0; nt < 5; ++nt) {
        const int neuron = nt * 16 + lrow;
        const float bias = b1[neuron];
#pragma unroll
        for (int r = 0; r < 4; ++r) {
            float v = fmaxf(acc1[nt][r] + bias, 0.f);
            h1t[wave][neuron >> 3][lg * 4 + r][neuron & 7] = (f16)v;
        }
    }
    // (compiler inserts lgkmcnt before dependent ds_read; wave-private tile,
    //  no __syncthreads needed)

    // ---- GEMM2: [16 x 96k] x [96k x 48] ----
    f32x4 acc2[3] = {zero4, zero4, zero4};
#pragma unroll
    for (int ks = 0; ks < 3; ++ks) {
        f16x8 a = *reinterpret_cast<const f16x8*>(&h1t[wave][ks * 4 + lg][lrow][0]);
#pragma unroll
        for (int nt = 0; nt < 3; ++nt)
            acc2[nt] = __builtin_amdgcn_mfma_f32_16x16x32_f16(
                a, bfrag[(WF2_OFF / 8) + (ks * 3 + nt) * 64 + lane], acc2[nt], 0, 0, 0);
    }
#pragma unroll
    for (int nt = 0; nt < 3; ++nt) {
        const int nn = nt * 16 + lrow;
        const float bias = (nn < 40) ? b2[nn] : 0.f;
#pragma unroll
        for (int r = 0; r < 4; ++r) {
            float v = fmaxf(acc2[nt][r] + bias, 0.f);
            if (nn < 40) h2t[wave][nn >> 3][lg * 4 + r][nn & 7] = (f16)v;
        }
    }

    // ---- GEMM3: [16 x 64k] x [64k x 32] ----
    f32x4 acc3[2] = {zero4, zero4};
#pragma unroll
    for (int ks = 0; ks < 2; ++ks) {
        f16x8 a = *reinterpret_cast<const f16x8*>(&h2t[wave][ks * 4 + lg][lrow][0]);
#pragma unroll
        for (int nt = 0; nt < 2; ++nt)
            acc3[nt] = __builtin_amdgcn_mfma_f32_16x16x32_f16(
                a, bfrag[(WF3_OFF / 8) + (ks * 2 + nt) * 64 + lane], acc3[nt], 0, 0, 0);
    }
#pragma unroll
    for (int nt = 0; nt < 2; ++nt) {
        const int col = nt * 16 + lrow;
        if (col < 21) {
            const float bias = b3[col];
#pragma unroll
            for (int r = 0; r < 4; ++r)
                out[(size_t)(ev0 + lg * 4 + r) * 21 + col] = acc3[nt][r] + bias;
        }
    }
}

extern "C" void kernel_launch(void* const* d_in, const int* in_sizes, int n_in,
                              void* d_out, int out_size, void* d_ws, size_t ws_size,
                              hipStream_t stream) {
    const float* x  = (const float*)d_in[0];
    const float* Wl = (const float*)d_in[1];
    const float* bl = (const float*)d_in[2];
    const float* W1 = (const float*)d_in[3];
    const float* b1 = (const float*)d_in[4];
    const float* W2 = (const float*)d_in[5];
    const float* b2 = (const float*)d_in[6];
    const float* W3 = (const float*)d_in[7];
    const float* b3 = (const float*)d_in[8];
    float* out = (float*)d_out;

    const int n = in_sizes[0] / 240;   // events (100000)
    const int n_trip = n * 20;

    f16* s16 = (f16*)d_ws;                          // [n][32] f16 = 6.4 MB
    f16* wf  = s16 + (size_t)n * 32;                // [WF_TOTAL] f16 (16B-aligned)

    prep_kernel<<<1, 256, 0, stream>>>(W1, W2, W3, wf);

    {
        const int block = 256;
        const int grid = (n_trip + block - 1) / block;
        score_kernel<<<grid, block, 0, stream>>>(x, Wl, bl, s16, n_trip);
    }
    {
        const int block = 256;                      // 4 waves x 16 events
        const int grid = (n + 64 - 1) / 64;
        mlp_mfma_kernel<<<grid, block, 0, stream>>>(s16, wf, b1, b2, b3, out, n);
    }
}